// Round 10
// baseline (653.268 us; speedup 1.0000x reference)
//
#include <hip/hip_runtime.h>

// EdgeCNN (DynamicEdgeConv): N=20000, F=64, H=128, K=6 (incl self). All f32.
// ROUND-14: kill the spills by pinning waves/EU BOTH sides.
//   Round-13 post-mortem: __launch_bounds__(256,2) sets only MIN waves/EU;
//   with no max, the scheduler targeted 4 waves/EU -> VGPR_Count=128 < the
//   ~230 working set (96 B-frags + 48 A + 32 acc + ladders) -> scratch
//   spills: WRITE_SIZE 2.1 -> 32.5 MB/dispatch, FETCH 37 -> 54 MB, MfmaUtil
//   stuck at 26%. Fix: __attribute__((amdgpu_waves_per_eu(2,2))) -- min 2
//   (VGPR cap 256 >= demand), max 2 (allocator must NOT shrink registers to
//   chase occupancy). Everything else byte-identical to the verified round-13
//   (4-wave blocks, disjoint tile quarters, LDS lex-merge, nc=3 chunks).
//   MFMA floor for the 6-term scheme: 308 GFLOP / 2.5 PF = 123 us chip-wide.

#define N_NODES 20000
#define FDIM 64
#define KNN 6
#define HID 128
#define N_PAD 20480
#define NTILES 625      // 20000/32 exactly
#define PREP_TILES 626  // +1 zero pad tile (B-side for wslot 312)
#define NWSLOT 313      // ceil(20000/64): 64 centers (2 B-tiles) per block
#define NCHUNK 3
#define TPC 209         // ceil(625/3); chunks cover 209/209/207 tiles
#define RPB 256
#define TILE_J 64
#define MAX_CHUNKS 10

typedef __attribute__((ext_vector_type(8))) short short8;
typedef __attribute__((ext_vector_type(16))) float f32x16;

#define MFMAB(A, B, C) __builtin_amdgcn_mfma_f32_32x32x16_bf16((A), (B), (C), 0, 0, 0)
#define ROFF(r) (((r) & 3) + 8 * ((r) >> 2))

// Sorted-ascending 6-slot insert; strict '<' => earlier (lower-j) candidate
// wins ties when scanned in ascending j, matching jax.lax.top_k stability.
#define INSERT_CAND(bd, bj, dv, jv) do {                                      \
  if ((dv) < bd[5]) {                                                         \
    const bool c0 = (dv) < bd[0], c1 = (dv) < bd[1], c2 = (dv) < bd[2];       \
    const bool c3 = (dv) < bd[3], c4 = (dv) < bd[4];                          \
    bd[5] = c4 ? bd[4] : (dv);              bj[5] = c4 ? bj[4] : (jv);        \
    bd[4] = c4 ? (c3 ? bd[3] : (dv)) : bd[4]; bj[4] = c4 ? (c3 ? bj[3] : (jv)) : bj[4]; \
    bd[3] = c3 ? (c2 ? bd[2] : (dv)) : bd[3]; bj[3] = c3 ? (c2 ? bj[2] : (jv)) : bj[3]; \
    bd[2] = c2 ? (c1 ? bd[1] : (dv)) : bd[2]; bj[2] = c2 ? (c1 ? bj[1] : (jv)) : bj[2]; \
    bd[1] = c1 ? (c0 ? bd[0] : (dv)) : bd[1]; bj[1] = c1 ? (c0 ? bj[0] : (jv)) : bj[1]; \
    bd[0] = c0 ? (dv) : bd[0];              bj[0] = c0 ? (jv) : bj[0];        \
  }                                                                           \
} while (0)

#define LEXLT(dv, jv, ds, js) (((dv) < (ds)) || ((dv) == (ds) && (jv) < (js)))
#define INSERT_TIE(bd, bj, dv, jv) do {                                       \
  if (LEXLT((dv), (jv), bd[5], bj[5])) {                                      \
    const bool c0 = LEXLT((dv), (jv), bd[0], bj[0]);                          \
    const bool c1 = LEXLT((dv), (jv), bd[1], bj[1]);                          \
    const bool c2 = LEXLT((dv), (jv), bd[2], bj[2]);                          \
    const bool c3 = LEXLT((dv), (jv), bd[3], bj[3]);                          \
    const bool c4 = LEXLT((dv), (jv), bd[4], bj[4]);                          \
    bd[5] = c4 ? bd[4] : (dv);              bj[5] = c4 ? bj[4] : (jv);        \
    bd[4] = c4 ? (c3 ? bd[3] : (dv)) : bd[4]; bj[4] = c4 ? (c3 ? bj[3] : (jv)) : bj[4]; \
    bd[3] = c3 ? (c2 ? bd[2] : (dv)) : bd[3]; bj[3] = c3 ? (c2 ? bj[2] : (jv)) : bj[3]; \
    bd[2] = c2 ? (c1 ? bd[1] : (dv)) : bd[2]; bj[2] = c2 ? (c1 ? bj[1] : (jv)) : bj[2]; \
    bd[1] = c1 ? (c0 ? bd[0] : (dv)) : bd[1]; bj[1] = c1 ? (c0 ? bj[0] : (jv)) : bj[1]; \
    bd[0] = c0 ? (dv) : bd[0];              bj[0] = c0 ? (jv) : bj[0];        \
  }                                                                           \
} while (0)

__device__ __forceinline__ f32x16 zero16() {
  f32x16 v;
#pragma unroll
  for (int i = 0; i < 16; ++i) v[i] = 0.f;
  return v;
}

__device__ __forceinline__ unsigned short bf16_rne(float x) {
  unsigned u = __float_as_uint(x);
  u += 0x7fffu + ((u >> 16) & 1u);
  return (unsigned short)(u >> 16);
}
__device__ __forceinline__ float bf16_tof(unsigned short h) {
  return __uint_as_float(((unsigned)h) << 16);
}

// ---------------------------------------------------------------------------
// Prep: sq + exact 3-term bf16 split (x = a+b+c), fragment-major layout:
// element (tile, ks, lane=(khalf<<5)|row, j) at tile*2048 + ks*512 + lane*8+j
// with feature = ks*16 + khalf*8 + j. Tile 625 is zeroed (pad).
// ---------------------------------------------------------------------------
__global__ void prep_kernel(const float* __restrict__ x, short* __restrict__ xa,
                            short* __restrict__ xb, short* __restrict__ xc,
                            float* __restrict__ sq) {
  const int n = blockIdx.x * blockDim.x + threadIdx.x;
  if (n >= PREP_TILES * 32) return;
  const int tile = n >> 5, row = n & 31;
  unsigned short a[FDIM], b[FDIM], c[FDIM];
  float s = 0.f;
  if (n < N_NODES) {
    const float4* r4 = (const float4*)(x + (size_t)n * FDIM);
#pragma unroll
    for (int q = 0; q < 16; ++q) {
      const float4 v = r4[q];
      const float vv[4] = {v.x, v.y, v.z, v.w};
#pragma unroll
      for (int e = 0; e < 4; ++e) {
        const float xv = vv[e];
        s = fmaf(xv, xv, s);
        const unsigned short ua = bf16_rne(xv);
        const float r1 = xv - bf16_tof(ua);      // exact
        const unsigned short ub = bf16_rne(r1);
        const float r2 = r1 - bf16_tof(ub);      // exact
        a[q * 4 + e] = ua; b[q * 4 + e] = ub; c[q * 4 + e] = bf16_rne(r2);
      }
    }
  } else {
#pragma unroll
    for (int f = 0; f < FDIM; ++f) { a[f] = 0; b[f] = 0; c[f] = 0; }
    s = __builtin_inff();
  }
  sq[n] = s;
#pragma unroll
  for (int ks = 0; ks < 4; ++ks) {
#pragma unroll
    for (int hh = 0; hh < 2; ++hh) {
      short8 va, vb, vc;
#pragma unroll
      for (int j = 0; j < 8; ++j) {
        const int f = ks * 16 + hh * 8 + j;
        va[j] = (short)a[f]; vb[j] = (short)b[f]; vc[j] = (short)c[f];
      }
      const size_t off = (size_t)tile * 2048 + ks * 512 + (size_t)((hh << 5) | row) * 8;
      *(short8*)(xa + off) = va;
      *(short8*)(xb + off) = vb;
      *(short8*)(xc + off) = vc;
    }
  }
}

// ---------------------------------------------------------------------------
// bf16 MFMA kNN scan: 4-wave blocks; waves split the chunk's tile range.
// ---------------------------------------------------------------------------
__device__ __forceinline__ void load_frag(const short* __restrict__ xa,
                                          const short* __restrict__ xb,
                                          const short* __restrict__ xc, int t,
                                          int lane, short8 (&Fa)[4],
                                          short8 (&Fb)[4], short8 (&Fc)[4]) {
  const size_t tb = (size_t)t * 2048 + (size_t)lane * 8;
#pragma unroll
  for (int ks = 0; ks < 4; ++ks) {
    Fa[ks] = *(const short8*)(xa + tb + ks * 512);
    Fb[ks] = *(const short8*)(xb + tb + ks * 512);
    Fc[ks] = *(const short8*)(xc + tb + ks * 512);
  }
}

// Selection (verified): fused min/argmin/runner-up + rare exact full ladder.
__device__ __forceinline__ void select6(const f32x16& acc,
                                        const float (&sqa)[16], int jbase,
                                        float (&bd)[KNN], int (&bj)[KNN]) {
  float key[16];
#pragma unroll
  for (int r = 0; r < 16; ++r) key[r] = fmaf(-2.f, acc[r], sqa[r]);  // sq_j-2dot
  float m0 = key[0], m1 = __builtin_inff();
  int j0 = jbase + ROFF(0);
#pragma unroll
  for (int r = 1; r < 16; ++r) {
    const float kr = key[r];
    const bool lt = kr < m0;
    m1 = fminf(m1, lt ? m0 : kr);
    j0 = lt ? (jbase + ROFF(r)) : j0;
    m0 = lt ? kr : m0;
  }
  if (__any(m0 < bd[5])) {
    if (__any(m1 < bd[5])) {
#pragma unroll
      for (int r = 0; r < 16; ++r) { INSERT_CAND(bd, bj, key[r], jbase + ROFF(r)); }
    } else {
      INSERT_CAND(bd, bj, m0, j0);
    }
  }
}

// Two interleaved MFMA chains (per-chain order identical to the verified
// comp_tile: aa, ab, ba, ac, ca, bb per ks) + both selections.
__device__ __forceinline__ void comp_tile2(
    const short8 (&Aa)[4], const short8 (&Ab)[4], const short8 (&Ac)[4],
    const short8 (&B0a)[4], const short8 (&B0b)[4], const short8 (&B0c)[4],
    const short8 (&B1a)[4], const short8 (&B1b)[4], const short8 (&B1c)[4],
    const float* __restrict__ sq, int t, int h, float (&bd0)[KNN],
    int (&bj0)[KNN], float (&bd1)[KNN], int (&bj1)[KNN]) {
  const int sb = t * 32 + 4 * h;
  float4 S4[4];
#pragma unroll
  for (int g = 0; g < 4; ++g) S4[g] = *(const float4*)(sq + sb + 8 * g);

  f32x16 ac0 = zero16(), ac1 = zero16();
#pragma unroll
  for (int ks = 0; ks < 4; ++ks) {
    ac0 = MFMAB(Aa[ks], B0a[ks], ac0);
    ac1 = MFMAB(Aa[ks], B1a[ks], ac1);
    ac0 = MFMAB(Aa[ks], B0b[ks], ac0);
    ac1 = MFMAB(Aa[ks], B1b[ks], ac1);
    ac0 = MFMAB(Ab[ks], B0a[ks], ac0);
    ac1 = MFMAB(Ab[ks], B1a[ks], ac1);
    ac0 = MFMAB(Aa[ks], B0c[ks], ac0);
    ac1 = MFMAB(Aa[ks], B1c[ks], ac1);
    ac0 = MFMAB(Ac[ks], B0a[ks], ac0);
    ac1 = MFMAB(Ac[ks], B1a[ks], ac1);
    ac0 = MFMAB(Ab[ks], B0b[ks], ac0);
    ac1 = MFMAB(Ab[ks], B1b[ks], ac1);
  }
  const float sqa[16] = {S4[0].x, S4[0].y, S4[0].z, S4[0].w,
                         S4[1].x, S4[1].y, S4[1].z, S4[1].w,
                         S4[2].x, S4[2].y, S4[2].z, S4[2].w,
                         S4[3].x, S4[3].y, S4[3].z, S4[3].w};
  const int jbase = t * 32 + 4 * h;
  select6(ac0, sqa, jbase, bd0, bj0);
  select6(ac1, sqa, jbase, bd1, bj1);
}

__device__ __forceinline__ void xmerge(float (&bd)[KNN], int (&bj)[KNN]) {
  float od[KNN];
  int oj[KNN];
#pragma unroll
  for (int k = 0; k < KNN; ++k) {
    od[k] = __shfl_xor(bd[k], 32);
    oj[k] = __shfl_xor(bj[k], 32);
  }
#pragma unroll
  for (int k = 0; k < KNN; ++k) INSERT_TIE(bd, bj, od[k], oj[k]);
}

__global__ __launch_bounds__(256)
__attribute__((amdgpu_waves_per_eu(2, 2)))  // pin BOTH sides: VGPR cap 256,
                                            // and no occupancy-chasing shrink
void knn_bf16_kernel(
    const short* __restrict__ xa, const short* __restrict__ xb,
    const short* __restrict__ xc, const float* __restrict__ sq,
    float* __restrict__ cand_d, unsigned short* __restrict__ cand_js,
    int* __restrict__ knn_idx, int nchunks) {
  __shared__ float lds_d[3][2][KNN][32];
  __shared__ int lds_j[3][2][KNN][32];
  const int tid = threadIdx.x;
  const int lane = tid & 63;
  const int w = tid >> 6;        // wave 0..3 within block
  const int wslot = blockIdx.x;  // 0..312
  const int jc = blockIdx.y;     // 0..nchunks-1
  const int h = lane >> 5, col = lane & 31;
  const int ct0 = wslot * 2, ct1 = ct0 + 1;  // ct1 <= 625 (zero pad tile)

  // Two B-tiles (64 centers) resident in VGPRs; same for all 4 waves.
  short8 B0a[4], B0b[4], B0c[4], B1a[4], B1b[4], B1c[4];
  load_frag(xa, xb, xc, ct0, lane, B0a, B0b, B0c);
  load_frag(xa, xb, xc, ct1, lane, B1a, B1b, B1c);

  float bd0[KNN], bd1[KNN];
  int bj0[KNN], bj1[KNN];
#pragma unroll
  for (int k = 0; k < KNN; ++k) {
    bd0[k] = __builtin_inff(); bj0[k] = 0;
    bd1[k] = __builtin_inff(); bj1[k] = 0;
  }

  // This wave's quarter of the chunk's tile range.
  const int cbeg = jc * TPC;
  int cend = cbeg + TPC;
  if (cend > NTILES) cend = NTILES;
  const int span = cend - cbeg;
  const int tpw = (span + 3) >> 2;
  const int tbeg = cbeg + w * tpw;
  int tend = tbeg + tpw;
  if (tend > cend) tend = cend;

  for (int t = tbeg; t < tend; ++t) {
    short8 Aa[4], Ab[4], Ac[4];
    load_frag(xa, xb, xc, t, lane, Aa, Ab, Ac);
    comp_tile2(Aa, Ab, Ac, B0a, B0b, B0c, B1a, B1b, B1c, sq, t, h,
               bd0, bj0, bd1, bj1);
  }

  // Merge the two row-halves (lane <-> lane^32) lexicographically.
  xmerge(bd0, bj0);
  xmerge(bd1, bj1);

  // Cross-wave merge: waves 1-3 publish; wave 0 folds with lex tie-break
  // (order-independent, same semantics as the chunk merge).
  if (w > 0 && h == 0) {
#pragma unroll
    for (int k = 0; k < KNN; ++k) {
      lds_d[w - 1][0][k][col] = bd0[k]; lds_j[w - 1][0][k][col] = bj0[k];
      lds_d[w - 1][1][k][col] = bd1[k]; lds_j[w - 1][1][k][col] = bj1[k];
    }
  }
  __syncthreads();
  if (w == 0) {
#pragma unroll
    for (int ww = 0; ww < 3; ++ww) {
#pragma unroll
      for (int k = 0; k < KNN; ++k) {
        { const float dv = lds_d[ww][0][k][col]; const int jv = lds_j[ww][0][k][col];
          INSERT_TIE(bd0, bj0, dv, jv); }
        { const float dv = lds_d[ww][1][k][col]; const int jv = lds_j[ww][1][k][col];
          INSERT_TIE(bd1, bj1, dv, jv); }
      }
    }
    if (h == 0) {
      const int i0 = ct0 * 32 + col;  // < 20000 always
      const int i1 = i0 + 32;         // >= 20000 only for wslot 312
      if (nchunks == 1) {
#pragma unroll
        for (int k = 0; k < KNN; ++k) knn_idx[(size_t)i0 * KNN + k] = bj0[k];
        if (i1 < N_NODES) {
#pragma unroll
          for (int k = 0; k < KNN; ++k) knn_idx[(size_t)i1 * KNN + k] = bj1[k];
        }
      } else {
#pragma unroll
        for (int k = 0; k < KNN; ++k) {
          const size_t off = ((size_t)jc * KNN + k) * N_PAD + i0;
          cand_d[off] = bd0[k];
          cand_js[off] = (unsigned short)bj0[k];
        }
        if (i1 < N_NODES) {
#pragma unroll
          for (int k = 0; k < KNN; ++k) {
            const size_t off = ((size_t)jc * KNN + k) * N_PAD + i1;
            cand_d[off] = bd1[k];
            cand_js[off] = (unsigned short)bj1[k];
          }
        }
      }
    }
  }
}

// Merge u16-j chunk candidates (lex-tie INSERT via ascending-j discipline).
__global__ void knn_merge_u16_kernel(const float* __restrict__ cand_d,
                                     const unsigned short* __restrict__ cand_js,
                                     int* __restrict__ knn_idx, int nchunks) {
  const int i = blockIdx.x * blockDim.x + threadIdx.x;
  if (i >= N_NODES) return;
  float bd[KNN];
  int bj[KNN];
#pragma unroll
  for (int k = 0; k < KNN; ++k) { bd[k] = __builtin_inff(); bj[k] = 0; }
  for (int jc = 0; jc < nchunks; ++jc) {
#pragma unroll
    for (int k = 0; k < KNN; ++k) {
      const size_t off = ((size_t)jc * KNN + k) * N_PAD + i;
      const float d = cand_d[off];
      const int j = (int)cand_js[off];
      INSERT_CAND(bd, bj, d, j);
    }
  }
#pragma unroll
  for (int k = 0; k < KNN; ++k) knn_idx[(size_t)i * KNN + k] = bj[k];
}

// ---------------------------------------------------------------------------
// Fallback VALU path (proven round-4) -- tiny-ws only.
// ---------------------------------------------------------------------------
__global__ void sq_kernel(const float* __restrict__ x, float* __restrict__ sq) {
  const int i = blockIdx.x * blockDim.x + threadIdx.x;
  if (i >= N_NODES) return;
  const float4* r4 = (const float4*)(x + (size_t)i * FDIM);
  float s = 0.f;
#pragma unroll
  for (int q = 0; q < 16; ++q) {
    const float4 a = r4[q];
    s = fmaf(a.x, a.x, s);
    s = fmaf(a.y, a.y, s);
    s = fmaf(a.z, a.z, s);
    s = fmaf(a.w, a.w, s);
  }
  sq[i] = s;
}

__global__ __launch_bounds__(RPB, 2) void knn_partial_kernel(
    const float* __restrict__ x, const float* __restrict__ sq,
    float* __restrict__ cand_d, int* __restrict__ cand_j,
    int* __restrict__ knn_idx, int jchunk, int nchunks) {
  __shared__ __align__(16) float xs[TILE_J][FDIM + 4];
  __shared__ float sqs[TILE_J];
  const int tid = threadIdx.x;
  const int i = blockIdx.x * RPB + tid;
  const bool valid = i < N_NODES;
  const int jc = blockIdx.y;

  float xi[FDIM];
  float sqi = 0.f;
  if (valid) {
    const float4* r4 = (const float4*)(x + (size_t)i * FDIM);
#pragma unroll
    for (int q = 0; q < 16; ++q) {
      const float4 a = r4[q];
      xi[q * 4 + 0] = a.x; xi[q * 4 + 1] = a.y;
      xi[q * 4 + 2] = a.z; xi[q * 4 + 3] = a.w;
    }
    sqi = sq[i];
  } else {
#pragma unroll
    for (int f = 0; f < FDIM; ++f) xi[f] = 0.f;
  }
#pragma unroll
  for (int f = 0; f < FDIM; ++f) asm volatile("" : "+v"(xi[f]));

  float bd[KNN];
  int bj[KNN];
#pragma unroll
  for (int k = 0; k < KNN; ++k) { bd[k] = __builtin_inff(); bj[k] = 0; }

  const int jcbase = jc * jchunk;
  for (int t0 = 0; t0 < jchunk; t0 += TILE_J) {
    const int jt = jcbase + t0;
    __syncthreads();
    {
      const int jj = tid >> 2;
      const int f0 = (tid & 3) * 16;
      const int j = jt + jj;
      float4* dst = (float4*)&xs[jj][f0];
      if (j < N_NODES) {
        const float4* src = (const float4*)(x + (size_t)j * FDIM + f0);
        dst[0] = src[0];
        dst[1] = src[1];
        dst[2] = src[2];
        dst[3] = src[3];
      } else {
        const float4 z = make_float4(0.f, 0.f, 0.f, 0.f);
        dst[0] = z; dst[1] = z; dst[2] = z; dst[3] = z;
      }
      if (tid < TILE_J) {
        const int j2 = jt + tid;
        sqs[tid] = (j2 < N_NODES) ? sq[j2] : 0.f;
      }
    }
    __syncthreads();
    const int rem = N_NODES - jt;
    const int jmax = rem < TILE_J ? rem : TILE_J;
    for (int jj = 0; jj < jmax; ++jj) {
      const float4* xr4 = (const float4*)&xs[jj][0];
      float dot = 0.f;
#pragma unroll
      for (int q = 0; q < 16; ++q) {
        const float4 v = xr4[q];
        dot = fmaf(xi[q * 4 + 0], v.x, dot);
        dot = fmaf(xi[q * 4 + 1], v.y, dot);
        dot = fmaf(xi[q * 4 + 2], v.z, dot);
        dot = fmaf(xi[q * 4 + 3], v.w, dot);
      }
      const float d = fmaf(-2.f, dot, sqi + sqs[jj]);
      const int j = jt + jj;
      INSERT_CAND(bd, bj, d, j);
    }
  }

  if (valid) {
    if (nchunks == 1) {
#pragma unroll
      for (int k = 0; k < KNN; ++k) knn_idx[(size_t)i * KNN + k] = bj[k];
    } else {
#pragma unroll
      for (int k = 0; k < KNN; ++k) {
        const size_t off = ((size_t)jc * KNN + k) * N_PAD + i;
        cand_d[off] = bd[k];
        cand_j[off] = bj[k];
      }
    }
  }
}

__global__ void knn_merge_kernel(const float* __restrict__ cand_d,
                                 const int* __restrict__ cand_j,
                                 int* __restrict__ knn_idx, int nchunks) {
  const int i = blockIdx.x * blockDim.x + threadIdx.x;
  if (i >= N_NODES) return;
  float bd[KNN];
  int bj[KNN];
#pragma unroll
  for (int k = 0; k < KNN; ++k) { bd[k] = __builtin_inff(); bj[k] = 0; }
  for (int jc = 0; jc < nchunks; ++jc) {
#pragma unroll
    for (int k = 0; k < KNN; ++k) {
      const size_t off = ((size_t)jc * KNN + k) * N_PAD + i;
      const float d = cand_d[off];
      const int j = cand_j[off];
      INSERT_CAND(bd, bj, d, j);
    }
  }
#pragma unroll
  for (int k = 0; k < KNN; ++k) knn_idx[(size_t)i * KNN + k] = bj[k];
}

__global__ __launch_bounds__(HID) void mlp_kernel(
    const float* __restrict__ x, const int* __restrict__ knn_idx,
    const float* __restrict__ W1, const float* __restrict__ b1,
    const float* __restrict__ W2, const float* __restrict__ b2,
    float* __restrict__ out) {
  __shared__ float xi_s[FDIM];
  __shared__ float xd_s[KNN][FDIM];
  __shared__ float h1_s[KNN][HID];
  __shared__ int nb[KNN];
  const int i = blockIdx.x;
  const int t = threadIdx.x;
  if (t < KNN) {
    const int v = knn_idx[(size_t)i * KNN + t];
    nb[t] = ((unsigned)v < (unsigned)N_NODES) ? v : 0;  // clamp: cannot fault
  }
  if (t < FDIM) xi_s[t] = x[(size_t)i * FDIM + t];
  __syncthreads();
  for (int e = t; e < KNN * FDIM; e += HID) {
    const int k = e >> 6;
    const int f = e & 63;
    xd_s[k][f] = x[(size_t)nb[k] * FDIM + f] - xi_s[f];
  }
  __syncthreads();

  float s0 = b1[t];
  for (int f = 0; f < FDIM; ++f) {
    const float w = W1[f * HID + t];
    s0 = fmaf(xi_s[f], w, s0);
  }
  float acc[KNN];
#pragma unroll
  for (int k = 0; k < KNN; ++k) acc[k] = s0;
  for (int f = 0; f < FDIM; ++f) {
    const float w = W1[(FDIM + f) * HID + t];
#pragma unroll
    for (int k = 0; k < KNN; ++k) acc[k] = fmaf(xd_s[k][f], w, acc[k]);
  }
#pragma unroll
  for (int k = 0; k < KNN; ++k) h1_s[k][t] = fmaxf(acc[k], 0.f);
  __syncthreads();

  float acc2[KNN];
  const float bb = b2[t];
#pragma unroll
  for (int k = 0; k < KNN; ++k) acc2[k] = bb;
  for (int h = 0; h < HID; ++h) {
    const float w = W2[h * HID + t];
#pragma unroll
    for (int k = 0; k < KNN; ++k) acc2[k] = fmaf(h1_s[k][h], w, acc2[k]);
  }
  float m = acc2[0];
#pragma unroll
  for (int k = 1; k < KNN; ++k) m = fmaxf(m, acc2[k]);
  out[(size_t)i * HID + t] = m;
}

extern "C" void kernel_launch(void* const* d_in, const int* in_sizes, int n_in,
                              void* d_out, int out_size, void* d_ws, size_t ws_size,
                              hipStream_t stream) {
  const float* x  = (const float*)d_in[0];
  const float* W1 = (const float*)d_in[2];
  const float* b1 = (const float*)d_in[3];
  const float* W2 = (const float*)d_in[4];
  const float* b2 = (const float*)d_in[5];
  float* out = (float*)d_out;
  char* ws = (char*)d_ws;
  const size_t PER_CHUNK = (size_t)KNN * N_PAD * 8;  // 983,040 B (fallback)

  if (ws_size >= 0x994000) {
    // MFMA layout (10,043,392 B required; inferred ws >= 10,419,840):
    //   0x000000 sq      (20032 f32 = 0x13900)
    //   0x020000 xa      (626*2048 s16 = 2,564,096 B) -> 0x292000
    //   0x292000 xb      -> 0x504000
    //   0x504000 xc      -> 0x776000
    //   0x776000 cand_d  (3*6*20480 f32 = 1,474,560 B) -> 0x8DE000
    //   0x8E0000 cand_js (3*6*20480 u16 = 737,280 B)  -> 0x994000
    //   knn aliases xa at 0x20000 (xa dead after the scan).
    float* sq   = (float*)ws;
    short* xa   = (short*)(ws + 0x20000);
    short* xb   = (short*)(ws + 0x292000);
    short* xc   = (short*)(ws + 0x504000);
    float* cand_d = (float*)(ws + 0x776000);
    unsigned short* cand_js = (unsigned short*)(ws + 0x8E0000);
    int* knn = (int*)(ws + 0x20000);

    prep_kernel<<<dim3((PREP_TILES * 32 + 255) / 256), dim3(256), 0, stream>>>(
        x, xa, xb, xc, sq);
    knn_bf16_kernel<<<dim3(NWSLOT, NCHUNK), dim3(256), 0, stream>>>(
        xa, xb, xc, sq, cand_d, cand_js, knn, NCHUNK);
    knn_merge_u16_kernel<<<dim3((N_NODES + 255) / 256), dim3(256), 0, stream>>>(
        cand_d, cand_js, knn, NCHUNK);
    mlp_kernel<<<dim3(N_NODES), dim3(HID), 0, stream>>>(x, knn, W1, b1, W2, b2, out);
  } else {
    // Fallback: round-4 layout (sq | knn | cand at 0x90000)
    float* sq = (float*)ws;
    int* knn  = (int*)(ws + (size_t)N_PAD * 4);
    const size_t BASE = 0x90000;
    int nc = 1;
    if (ws_size > BASE + PER_CHUNK) {
      size_t fit = (ws_size - BASE) / PER_CHUNK;
      nc = fit < (size_t)MAX_CHUNKS ? (int)fit : MAX_CHUNKS;
      if (nc < 1) nc = 1;
    }
    int jchunk = ((N_NODES + nc - 1) / nc + TILE_J - 1) / TILE_J * TILE_J;
    float* cand_d = (float*)(ws + BASE);
    int* cand_j = (int*)(ws + BASE + (size_t)nc * KNN * N_PAD * 4);

    sq_kernel<<<dim3((N_NODES + 255) / 256), dim3(256), 0, stream>>>(x, sq);
    knn_partial_kernel<<<dim3((N_NODES + RPB - 1) / RPB, nc), dim3(RPB), 0, stream>>>(
        x, sq, cand_d, cand_j, knn, jchunk, nc);
    if (nc > 1) {
      knn_merge_kernel<<<dim3((N_NODES + 255) / 256), dim3(256), 0, stream>>>(
          cand_d, cand_j, knn, nc);
    }
    mlp_kernel<<<dim3(N_NODES), dim3(HID), 0, stream>>>(x, knn, W1, b1, W2, b2, out);
  }
}

// Round 11
// 638.903 us; speedup vs baseline: 1.0225x; 1.0225x over previous
//
#include <hip/hip_runtime.h>

// EdgeCNN (DynamicEdgeConv): N=20000, F=64, H=128, K=6 (incl self). All f32.
// ROUND-15: stop fighting the register allocator -- shrink the working set.
//   Rounds 13/14: allocator pins VGPR=128 regardless of hints (launch_bounds
//   min / waves_per_eu(2,2) both ignored) and spills the ~230-reg working
//   set (WRITE_SIZE 32.5 MB = scratch). Fix: make 128 sufficient:
//   - 1 B-tile per wave (48 VGPR B-frags, 16 acc, 12 ladder)
//   - A-tile staged in LDS per block (12 KB), read ks-by-ks (12 transient
//     VGPRs) -> no 48-reg A block, and 4x less global A-traffic
//   - S4/sqa loaded AFTER the MFMA chain (cuts live-range overlap)
//   - waves own disjoint centers -> NO cross-wave merge at all
//   Peak live ~115 regs < 128. MFMA chain order / select6 / xmerge / u16
//   cand+merge BYTE-IDENTICAL to the on-device-verified versions.
//   MFMA floor for the 6-term scheme: 308 GFLOP / 2.5 PF = 123 us chip-wide.

#define N_NODES 20000
#define FDIM 64
#define KNN 6
#define HID 128
#define N_PAD 20480
#define NTILES 625      // A-tiles: 20000/32 exactly
#define PREP_TILES 628  // B-side pad: 157 blocks x 4 waves = 628 tiles
#define NBLK 157        // blocks per chunk (4 B-tiles = 128 centers each)
#define NCHUNK 3
#define TPC 209         // ceil(625/3); chunks cover 209/209/207 tiles
#define RPB 256
#define TILE_J 64
#define MAX_CHUNKS 10

typedef __attribute__((ext_vector_type(8))) short short8;
typedef __attribute__((ext_vector_type(16))) float f32x16;

#define MFMAB(A, B, C) __builtin_amdgcn_mfma_f32_32x32x16_bf16((A), (B), (C), 0, 0, 0)
#define ROFF(r) (((r) & 3) + 8 * ((r) >> 2))

// Sorted-ascending 6-slot insert; strict '<' => earlier (lower-j) candidate
// wins ties when scanned in ascending j, matching jax.lax.top_k stability.
#define INSERT_CAND(bd, bj, dv, jv) do {                                      \
  if ((dv) < bd[5]) {                                                         \
    const bool c0 = (dv) < bd[0], c1 = (dv) < bd[1], c2 = (dv) < bd[2];       \
    const bool c3 = (dv) < bd[3], c4 = (dv) < bd[4];                          \
    bd[5] = c4 ? bd[4] : (dv);              bj[5] = c4 ? bj[4] : (jv);        \
    bd[4] = c4 ? (c3 ? bd[3] : (dv)) : bd[4]; bj[4] = c4 ? (c3 ? bj[3] : (jv)) : bj[4]; \
    bd[3] = c3 ? (c2 ? bd[2] : (dv)) : bd[3]; bj[3] = c3 ? (c2 ? bj[2] : (jv)) : bj[3]; \
    bd[2] = c2 ? (c1 ? bd[1] : (dv)) : bd[2]; bj[2] = c2 ? (c1 ? bj[1] : (jv)) : bj[2]; \
    bd[1] = c1 ? (c0 ? bd[0] : (dv)) : bd[1]; bj[1] = c1 ? (c0 ? bj[0] : (jv)) : bj[1]; \
    bd[0] = c0 ? (dv) : bd[0];              bj[0] = c0 ? (jv) : bj[0];        \
  }                                                                           \
} while (0)

#define LEXLT(dv, jv, ds, js) (((dv) < (ds)) || ((dv) == (ds) && (jv) < (js)))
#define INSERT_TIE(bd, bj, dv, jv) do {                                       \
  if (LEXLT((dv), (jv), bd[5], bj[5])) {                                      \
    const bool c0 = LEXLT((dv), (jv), bd[0], bj[0]);                          \
    const bool c1 = LEXLT((dv), (jv), bd[1], bj[1]);                          \
    const bool c2 = LEXLT((dv), (jv), bd[2], bj[2]);                          \
    const bool c3 = LEXLT((dv), (jv), bd[3], bj[3]);                          \
    const bool c4 = LEXLT((dv), (jv), bd[4], bj[4]);                          \
    bd[5] = c4 ? bd[4] : (dv);              bj[5] = c4 ? bj[4] : (jv);        \
    bd[4] = c4 ? (c3 ? bd[3] : (dv)) : bd[4]; bj[4] = c4 ? (c3 ? bj[3] : (jv)) : bj[4]; \
    bd[3] = c3 ? (c2 ? bd[2] : (dv)) : bd[3]; bj[3] = c3 ? (c2 ? bj[2] : (jv)) : bj[3]; \
    bd[2] = c2 ? (c1 ? bd[1] : (dv)) : bd[2]; bj[2] = c2 ? (c1 ? bj[1] : (jv)) : bj[2]; \
    bd[1] = c1 ? (c0 ? bd[0] : (dv)) : bd[1]; bj[1] = c1 ? (c0 ? bj[0] : (jv)) : bj[1]; \
    bd[0] = c0 ? (dv) : bd[0];              bj[0] = c0 ? (jv) : bj[0];        \
  }                                                                           \
} while (0)

__device__ __forceinline__ f32x16 zero16() {
  f32x16 v;
#pragma unroll
  for (int i = 0; i < 16; ++i) v[i] = 0.f;
  return v;
}

__device__ __forceinline__ unsigned short bf16_rne(float x) {
  unsigned u = __float_as_uint(x);
  u += 0x7fffu + ((u >> 16) & 1u);
  return (unsigned short)(u >> 16);
}
__device__ __forceinline__ float bf16_tof(unsigned short h) {
  return __uint_as_float(((unsigned)h) << 16);
}

// ---------------------------------------------------------------------------
// Prep: sq + exact 3-term bf16 split (x = a+b+c), fragment-major layout:
// element (tile, ks, lane=(khalf<<5)|row, j) at tile*2048 + ks*512 + lane*8+j
// with feature = ks*16 + khalf*8 + j. Tiles 625..627 zeroed (B-side pad).
// ---------------------------------------------------------------------------
__global__ void prep_kernel(const float* __restrict__ x, short* __restrict__ xa,
                            short* __restrict__ xb, short* __restrict__ xc,
                            float* __restrict__ sq) {
  const int n = blockIdx.x * blockDim.x + threadIdx.x;
  if (n >= PREP_TILES * 32) return;
  const int tile = n >> 5, row = n & 31;
  unsigned short a[FDIM], b[FDIM], c[FDIM];
  float s = 0.f;
  if (n < N_NODES) {
    const float4* r4 = (const float4*)(x + (size_t)n * FDIM);
#pragma unroll
    for (int q = 0; q < 16; ++q) {
      const float4 v = r4[q];
      const float vv[4] = {v.x, v.y, v.z, v.w};
#pragma unroll
      for (int e = 0; e < 4; ++e) {
        const float xv = vv[e];
        s = fmaf(xv, xv, s);
        const unsigned short ua = bf16_rne(xv);
        const float r1 = xv - bf16_tof(ua);      // exact
        const unsigned short ub = bf16_rne(r1);
        const float r2 = r1 - bf16_tof(ub);      // exact
        a[q * 4 + e] = ua; b[q * 4 + e] = ub; c[q * 4 + e] = bf16_rne(r2);
      }
    }
  } else {
#pragma unroll
    for (int f = 0; f < FDIM; ++f) { a[f] = 0; b[f] = 0; c[f] = 0; }
    s = __builtin_inff();
  }
  sq[n] = s;
#pragma unroll
  for (int ks = 0; ks < 4; ++ks) {
#pragma unroll
    for (int hh = 0; hh < 2; ++hh) {
      short8 va, vb, vc;
#pragma unroll
      for (int j = 0; j < 8; ++j) {
        const int f = ks * 16 + hh * 8 + j;
        va[j] = (short)a[f]; vb[j] = (short)b[f]; vc[j] = (short)c[f];
      }
      const size_t off = (size_t)tile * 2048 + ks * 512 + (size_t)((hh << 5) | row) * 8;
      *(short8*)(xa + off) = va;
      *(short8*)(xb + off) = vb;
      *(short8*)(xc + off) = vc;
    }
  }
}

// ---------------------------------------------------------------------------
// bf16 MFMA kNN scan: 4-wave blocks; A-tile staged in LDS (shared by all 4
// waves), each wave owns ONE B-tile (32 centers) -> disjoint outputs, no
// cross-wave merge. Working set ~115 VGPR < 128 by construction.
// ---------------------------------------------------------------------------
__device__ __forceinline__ void load_frag(const short* __restrict__ xa,
                                          const short* __restrict__ xb,
                                          const short* __restrict__ xc, int t,
                                          int lane, short8 (&Fa)[4],
                                          short8 (&Fb)[4], short8 (&Fc)[4]) {
  const size_t tb = (size_t)t * 2048 + (size_t)lane * 8;
#pragma unroll
  for (int ks = 0; ks < 4; ++ks) {
    Fa[ks] = *(const short8*)(xa + tb + ks * 512);
    Fb[ks] = *(const short8*)(xb + tb + ks * 512);
    Fc[ks] = *(const short8*)(xc + tb + ks * 512);
  }
}

// Selection (verified): fused min/argmin/runner-up + rare exact full ladder.
__device__ __forceinline__ void select6(const f32x16& acc,
                                        const float (&sqa)[16], int jbase,
                                        float (&bd)[KNN], int (&bj)[KNN]) {
  float key[16];
#pragma unroll
  for (int r = 0; r < 16; ++r) key[r] = fmaf(-2.f, acc[r], sqa[r]);  // sq_j-2dot
  float m0 = key[0], m1 = __builtin_inff();
  int j0 = jbase + ROFF(0);
#pragma unroll
  for (int r = 1; r < 16; ++r) {
    const float kr = key[r];
    const bool lt = kr < m0;
    m1 = fminf(m1, lt ? m0 : kr);
    j0 = lt ? (jbase + ROFF(r)) : j0;
    m0 = lt ? kr : m0;
  }
  if (__any(m0 < bd[5])) {
    if (__any(m1 < bd[5])) {
#pragma unroll
      for (int r = 0; r < 16; ++r) { INSERT_CAND(bd, bj, key[r], jbase + ROFF(r)); }
    } else {
      INSERT_CAND(bd, bj, m0, j0);
    }
  }
}

__device__ __forceinline__ void xmerge(float (&bd)[KNN], int (&bj)[KNN]) {
  float od[KNN];
  int oj[KNN];
#pragma unroll
  for (int k = 0; k < KNN; ++k) {
    od[k] = __shfl_xor(bd[k], 32);
    oj[k] = __shfl_xor(bj[k], 32);
  }
#pragma unroll
  for (int k = 0; k < KNN; ++k) INSERT_TIE(bd, bj, od[k], oj[k]);
}

__global__ __launch_bounds__(256, 2) void knn_bf16_kernel(
    const short* __restrict__ xa, const short* __restrict__ xb,
    const short* __restrict__ xc, const float* __restrict__ sq,
    float* __restrict__ cand_d, unsigned short* __restrict__ cand_js,
    int* __restrict__ knn_idx, int nchunks) {
  __shared__ __align__(16) short sa[2048];
  __shared__ __align__(16) short sb[2048];
  __shared__ __align__(16) short sc[2048];
  const int tid = threadIdx.x;
  const int lane = tid & 63;
  const int w = tid >> 6;              // wave 0..3
  const int ct = blockIdx.x * 4 + w;   // this wave's B-tile, 0..627 (>=625 pad)
  const int jc = blockIdx.y;           // 0..nchunks-1
  const int h = lane >> 5, col = lane & 31;

  // One B-tile (32 centers) resident in VGPRs for the whole chunk scan.
  short8 Ba[4], Bb[4], Bc[4];
  load_frag(xa, xb, xc, ct, lane, Ba, Bb, Bc);

  float bd[KNN];
  int bj[KNN];
#pragma unroll
  for (int k = 0; k < KNN; ++k) { bd[k] = __builtin_inff(); bj[k] = 0; }

  const int tbeg = jc * TPC;
  int tend = tbeg + TPC;
  if (tend > NTILES) tend = NTILES;

  const int t8 = tid * 8;  // this thread's 16B slice of the 4KB tile arrays
  for (int t = tbeg; t < tend; ++t) {
    const size_t tb = (size_t)t * 2048;
    __syncthreads();  // previous tile's LDS reads complete
    *(short8*)(sa + t8) = *(const short8*)(xa + tb + t8);
    *(short8*)(sb + t8) = *(const short8*)(xb + tb + t8);
    *(short8*)(sc + t8) = *(const short8*)(xc + tb + t8);
    __syncthreads();  // tile staged

    f32x16 acc = zero16();
    const int la8 = lane * 8;
#pragma unroll
    for (int ks = 0; ks < 4; ++ks) {
      // Per-ks transient A-frags from LDS (12 VGPRs, not 48).
      const short8 Aa = *(const short8*)(sa + ks * 512 + la8);
      const short8 Ab = *(const short8*)(sb + ks * 512 + la8);
      const short8 Ac = *(const short8*)(sc + ks * 512 + la8);
      // Chain order identical to the verified comp_tile: aa,ab,ba,ac,ca,bb.
      acc = MFMAB(Aa, Ba[ks], acc);
      acc = MFMAB(Aa, Bb[ks], acc);
      acc = MFMAB(Ab, Ba[ks], acc);
      acc = MFMAB(Aa, Bc[ks], acc);
      acc = MFMAB(Ac, Ba[ks], acc);
      acc = MFMAB(Ab, Bb[ks], acc);
    }
    // sq loads AFTER the chain: cuts register live-range overlap (sq is
    // L1/L2-hot, 80 KB); same values as the verified path.
    const int sbase = t * 32 + 4 * h;
    float4 S4[4];
#pragma unroll
    for (int g = 0; g < 4; ++g) S4[g] = *(const float4*)(sq + sbase + 8 * g);
    const float sqa[16] = {S4[0].x, S4[0].y, S4[0].z, S4[0].w,
                           S4[1].x, S4[1].y, S4[1].z, S4[1].w,
                           S4[2].x, S4[2].y, S4[2].z, S4[2].w,
                           S4[3].x, S4[3].y, S4[3].z, S4[3].w};
    select6(acc, sqa, t * 32 + 4 * h, bd, bj);
  }

  // Merge the two row-halves (lane <-> lane^32) lexicographically.
  xmerge(bd, bj);

  if (h == 0) {
    const int i = ct * 32 + col;  // >= 20000 only for pad tiles 625..627
    if (i < N_NODES) {
      if (nchunks == 1) {
#pragma unroll
        for (int k = 0; k < KNN; ++k) knn_idx[(size_t)i * KNN + k] = bj[k];
      } else {
#pragma unroll
        for (int k = 0; k < KNN; ++k) {
          const size_t off = ((size_t)jc * KNN + k) * N_PAD + i;
          cand_d[off] = bd[k];
          cand_js[off] = (unsigned short)bj[k];
        }
      }
    }
  }
}

// Merge u16-j chunk candidates (ascending jc = ascending j ranges preserves
// the lowest-j-wins tie discipline; per-chunk lists already sorted asc).
__global__ void knn_merge_u16_kernel(const float* __restrict__ cand_d,
                                     const unsigned short* __restrict__ cand_js,
                                     int* __restrict__ knn_idx, int nchunks) {
  const int i = blockIdx.x * blockDim.x + threadIdx.x;
  if (i >= N_NODES) return;
  float bd[KNN];
  int bj[KNN];
#pragma unroll
  for (int k = 0; k < KNN; ++k) { bd[k] = __builtin_inff(); bj[k] = 0; }
  for (int jc = 0; jc < nchunks; ++jc) {
#pragma unroll
    for (int k = 0; k < KNN; ++k) {
      const size_t off = ((size_t)jc * KNN + k) * N_PAD + i;
      const float d = cand_d[off];
      const int j = (int)cand_js[off];
      INSERT_CAND(bd, bj, d, j);
    }
  }
#pragma unroll
  for (int k = 0; k < KNN; ++k) knn_idx[(size_t)i * KNN + k] = bj[k];
}

// ---------------------------------------------------------------------------
// Fallback VALU path (proven round-4) -- tiny-ws only.
// ---------------------------------------------------------------------------
__global__ void sq_kernel(const float* __restrict__ x, float* __restrict__ sq) {
  const int i = blockIdx.x * blockDim.x + threadIdx.x;
  if (i >= N_NODES) return;
  const float4* r4 = (const float4*)(x + (size_t)i * FDIM);
  float s = 0.f;
#pragma unroll
  for (int q = 0; q < 16; ++q) {
    const float4 a = r4[q];
    s = fmaf(a.x, a.x, s);
    s = fmaf(a.y, a.y, s);
    s = fmaf(a.z, a.z, s);
    s = fmaf(a.w, a.w, s);
  }
  sq[i] = s;
}

__global__ __launch_bounds__(RPB, 2) void knn_partial_kernel(
    const float* __restrict__ x, const float* __restrict__ sq,
    float* __restrict__ cand_d, int* __restrict__ cand_j,
    int* __restrict__ knn_idx, int jchunk, int nchunks) {
  __shared__ __align__(16) float xs[TILE_J][FDIM + 4];
  __shared__ float sqs[TILE_J];
  const int tid = threadIdx.x;
  const int i = blockIdx.x * RPB + tid;
  const bool valid = i < N_NODES;
  const int jc = blockIdx.y;

  float xi[FDIM];
  float sqi = 0.f;
  if (valid) {
    const float4* r4 = (const float4*)(x + (size_t)i * FDIM);
#pragma unroll
    for (int q = 0; q < 16; ++q) {
      const float4 a = r4[q];
      xi[q * 4 + 0] = a.x; xi[q * 4 + 1] = a.y;
      xi[q * 4 + 2] = a.z; xi[q * 4 + 3] = a.w;
    }
    sqi = sq[i];
  } else {
#pragma unroll
    for (int f = 0; f < FDIM; ++f) xi[f] = 0.f;
  }
#pragma unroll
  for (int f = 0; f < FDIM; ++f) asm volatile("" : "+v"(xi[f]));

  float bd[KNN];
  int bj[KNN];
#pragma unroll
  for (int k = 0; k < KNN; ++k) { bd[k] = __builtin_inff(); bj[k] = 0; }

  const int jcbase = jc * jchunk;
  for (int t0 = 0; t0 < jchunk; t0 += TILE_J) {
    const int jt = jcbase + t0;
    __syncthreads();
    {
      const int jj = tid >> 2;
      const int f0 = (tid & 3) * 16;
      const int j = jt + jj;
      float4* dst = (float4*)&xs[jj][f0];
      if (j < N_NODES) {
        const float4* src = (const float4*)(x + (size_t)j * FDIM + f0);
        dst[0] = src[0];
        dst[1] = src[1];
        dst[2] = src[2];
        dst[3] = src[3];
      } else {
        const float4 z = make_float4(0.f, 0.f, 0.f, 0.f);
        dst[0] = z; dst[1] = z; dst[2] = z; dst[3] = z;
      }
      if (tid < TILE_J) {
        const int j2 = jt + tid;
        sqs[tid] = (j2 < N_NODES) ? sq[j2] : 0.f;
      }
    }
    __syncthreads();
    const int rem = N_NODES - jt;
    const int jmax = rem < TILE_J ? rem : TILE_J;
    for (int jj = 0; jj < jmax; ++jj) {
      const float4* xr4 = (const float4*)&xs[jj][0];
      float dot = 0.f;
#pragma unroll
      for (int q = 0; q < 16; ++q) {
        const float4 v = xr4[q];
        dot = fmaf(xi[q * 4 + 0], v.x, dot);
        dot = fmaf(xi[q * 4 + 1], v.y, dot);
        dot = fmaf(xi[q * 4 + 2], v.z, dot);
        dot = fmaf(xi[q * 4 + 3], v.w, dot);
      }
      const float d = fmaf(-2.f, dot, sqi + sqs[jj]);
      const int j = jt + jj;
      INSERT_CAND(bd, bj, d, j);
    }
  }

  if (valid) {
    if (nchunks == 1) {
#pragma unroll
      for (int k = 0; k < KNN; ++k) knn_idx[(size_t)i * KNN + k] = bj[k];
    } else {
#pragma unroll
      for (int k = 0; k < KNN; ++k) {
        const size_t off = ((size_t)jc * KNN + k) * N_PAD + i;
        cand_d[off] = bd[k];
        cand_j[off] = bj[k];
      }
    }
  }
}

__global__ void knn_merge_kernel(const float* __restrict__ cand_d,
                                 const int* __restrict__ cand_j,
                                 int* __restrict__ knn_idx, int nchunks) {
  const int i = blockIdx.x * blockDim.x + threadIdx.x;
  if (i >= N_NODES) return;
  float bd[KNN];
  int bj[KNN];
#pragma unroll
  for (int k = 0; k < KNN; ++k) { bd[k] = __builtin_inff(); bj[k] = 0; }
  for (int jc = 0; jc < nchunks; ++jc) {
#pragma unroll
    for (int k = 0; k < KNN; ++k) {
      const size_t off = ((size_t)jc * KNN + k) * N_PAD + i;
      const float d = cand_d[off];
      const int j = cand_j[off];
      INSERT_CAND(bd, bj, d, j);
    }
  }
#pragma unroll
  for (int k = 0; k < KNN; ++k) knn_idx[(size_t)i * KNN + k] = bj[k];
}

__global__ __launch_bounds__(HID) void mlp_kernel(
    const float* __restrict__ x, const int* __restrict__ knn_idx,
    const float* __restrict__ W1, const float* __restrict__ b1,
    const float* __restrict__ W2, const float* __restrict__ b2,
    float* __restrict__ out) {
  __shared__ float xi_s[FDIM];
  __shared__ float xd_s[KNN][FDIM];
  __shared__ float h1_s[KNN][HID];
  __shared__ int nb[KNN];
  const int i = blockIdx.x;
  const int t = threadIdx.x;
  if (t < KNN) {
    const int v = knn_idx[(size_t)i * KNN + t];
    nb[t] = ((unsigned)v < (unsigned)N_NODES) ? v : 0;  // clamp: cannot fault
  }
  if (t < FDIM) xi_s[t] = x[(size_t)i * FDIM + t];
  __syncthreads();
  for (int e = t; e < KNN * FDIM; e += HID) {
    const int k = e >> 6;
    const int f = e & 63;
    xd_s[k][f] = x[(size_t)nb[k] * FDIM + f] - xi_s[f];
  }
  __syncthreads();

  float s0 = b1[t];
  for (int f = 0; f < FDIM; ++f) {
    const float w = W1[f * HID + t];
    s0 = fmaf(xi_s[f], w, s0);
  }
  float acc[KNN];
#pragma unroll
  for (int k = 0; k < KNN; ++k) acc[k] = s0;
  for (int f = 0; f < FDIM; ++f) {
    const float w = W1[(FDIM + f) * HID + t];
#pragma unroll
    for (int k = 0; k < KNN; ++k) acc[k] = fmaf(xd_s[k][f], w, acc[k]);
  }
#pragma unroll
  for (int k = 0; k < KNN; ++k) h1_s[k][t] = fmaxf(acc[k], 0.f);
  __syncthreads();

  float acc2[KNN];
  const float bb = b2[t];
#pragma unroll
  for (int k = 0; k < KNN; ++k) acc2[k] = bb;
  for (int h = 0; h < HID; ++h) {
    const float w = W2[h * HID + t];
#pragma unroll
    for (int k = 0; k < KNN; ++k) acc2[k] = fmaf(h1_s[k][h], w, acc2[k]);
  }
  float m = acc2[0];
#pragma unroll
  for (int k = 1; k < KNN; ++k) m = fmaxf(m, acc2[k]);
  out[(size_t)i * HID + t] = m;
}

extern "C" void kernel_launch(void* const* d_in, const int* in_sizes, int n_in,
                              void* d_out, int out_size, void* d_ws, size_t ws_size,
                              hipStream_t stream) {
  const float* x  = (const float*)d_in[0];
  const float* W1 = (const float*)d_in[2];
  const float* b1 = (const float*)d_in[3];
  const float* W2 = (const float*)d_in[4];
  const float* b2 = (const float*)d_in[5];
  float* out = (float*)d_out;
  char* ws = (char*)d_ws;
  const size_t PER_CHUNK = (size_t)KNN * N_PAD * 8;  // 983,040 B (fallback)

  if (ws_size >= 0x998000) {
    // MFMA layout (10,059,776 B required; inferred ws >= 10,420,224):
    //   0x000000 sq      (20096 f32 used; 0x20000 reserved)
    //   0x020000 xa      (628*2048 s16 = 2,572,288 B) -> 0x294000
    //   0x294000 xb      -> 0x508000
    //   0x508000 xc      -> 0x77C000
    //   0x77C000 cand_d  (3*6*20480 f32 = 1,474,560 B) -> 0x8E4000
    //   0x8E4000 cand_js (3*6*20480 u16 = 737,280 B)  -> 0x998000
    //   knn aliases xa at 0x20000 (xa dead after the scan).
    float* sq   = (float*)ws;
    short* xa   = (short*)(ws + 0x20000);
    short* xb   = (short*)(ws + 0x294000);
    short* xc   = (short*)(ws + 0x508000);
    float* cand_d = (float*)(ws + 0x77C000);
    unsigned short* cand_js = (unsigned short*)(ws + 0x8E4000);
    int* knn = (int*)(ws + 0x20000);

    prep_kernel<<<dim3((PREP_TILES * 32 + 255) / 256), dim3(256), 0, stream>>>(
        x, xa, xb, xc, sq);
    knn_bf16_kernel<<<dim3(NBLK, NCHUNK), dim3(256), 0, stream>>>(
        xa, xb, xc, sq, cand_d, cand_js, knn, NCHUNK);
    knn_merge_u16_kernel<<<dim3((N_NODES + 255) / 256), dim3(256), 0, stream>>>(
        cand_d, cand_js, knn, NCHUNK);
    mlp_kernel<<<dim3(N_NODES), dim3(HID), 0, stream>>>(x, knn, W1, b1, W2, b2, out);
  } else {
    // Fallback: round-4 layout (sq | knn | cand at 0x90000)
    float* sq = (float*)ws;
    int* knn  = (int*)(ws + (size_t)N_PAD * 4);
    const size_t BASE = 0x90000;
    int nc = 1;
    if (ws_size > BASE + PER_CHUNK) {
      size_t fit = (ws_size - BASE) / PER_CHUNK;
      nc = fit < (size_t)MAX_CHUNKS ? (int)fit : MAX_CHUNKS;
      if (nc < 1) nc = 1;
    }
    int jchunk = ((N_NODES + nc - 1) / nc + TILE_J - 1) / TILE_J * TILE_J;
    float* cand_d = (float*)(ws + BASE);
    int* cand_j = (int*)(ws + BASE + (size_t)nc * KNN * N_PAD * 4);

    sq_kernel<<<dim3((N_NODES + 255) / 256), dim3(256), 0, stream>>>(x, sq);
    knn_partial_kernel<<<dim3((N_NODES + RPB - 1) / RPB, nc), dim3(RPB), 0, stream>>>(
        x, sq, cand_d, cand_j, knn, jchunk, nc);
    if (nc > 1) {
      knn_merge_kernel<<<dim3((N_NODES + 255) / 256), dim3(256), 0, stream>>>(
          cand_d, cand_j, knn, nc);
    }
    mlp_kernel<<<dim3(N_NODES), dim3(HID), 0, stream>>>(x, knn, W1, b1, W2, b2, out);
  }
}

// Round 12
// 594.032 us; speedup vs baseline: 1.0997x; 1.0755x over previous
//
#include <hip/hip_runtime.h>

// EdgeCNN (DynamicEdgeConv): N=20000, F=64, H=128, K=6 (incl self). All f32.
// ROUND-16: hide staging latency -- LDS double buffer, ONE barrier per tile.
//   Round-15 post-mortem: spills GONE (WRITE 32.5->2.1 MB, VGPR 80) but
//   MfmaUtil stuck at 27% == 2 blocks x 811 matrix-cyc / 5545 cyc-per-tile:
//   the serial stage->barrier->compute->barrier path (global latency + 2
//   full-block barriers per tile) is ~70% of each tile, and at 1.84
//   blocks/CU nothing fills the gap. Fix: 2x LDS buffers; per tile issue
//   next-tile loads into 12 regs, compute current from LDS, write regs to
//   the OTHER buffer, single barrier (writes never touch the buffer being
//   read; a buffer is fully barrier-separated from its rewrite). VGPR +12,
//   still < 128. MFMA chain / select6 / xmerge / cand+merge BYTE-IDENTICAL
//   to the on-device-verified versions.

#define N_NODES 20000
#define FDIM 64
#define KNN 6
#define HID 128
#define N_PAD 20480
#define NTILES 625      // A-tiles: 20000/32 exactly
#define PREP_TILES 628  // B-side pad: 157 blocks x 4 waves = 628 tiles
#define NBLK 157        // blocks per chunk (4 B-tiles = 128 centers each)
#define NCHUNK 3
#define TPC 209         // ceil(625/3); chunks cover 209/209/207 tiles
#define RPB 256
#define TILE_J 64
#define MAX_CHUNKS 10

typedef __attribute__((ext_vector_type(8))) short short8;
typedef __attribute__((ext_vector_type(16))) float f32x16;

#define MFMAB(A, B, C) __builtin_amdgcn_mfma_f32_32x32x16_bf16((A), (B), (C), 0, 0, 0)
#define ROFF(r) (((r) & 3) + 8 * ((r) >> 2))

// Sorted-ascending 6-slot insert; strict '<' => earlier (lower-j) candidate
// wins ties when scanned in ascending j, matching jax.lax.top_k stability.
#define INSERT_CAND(bd, bj, dv, jv) do {                                      \
  if ((dv) < bd[5]) {                                                         \
    const bool c0 = (dv) < bd[0], c1 = (dv) < bd[1], c2 = (dv) < bd[2];       \
    const bool c3 = (dv) < bd[3], c4 = (dv) < bd[4];                          \
    bd[5] = c4 ? bd[4] : (dv);              bj[5] = c4 ? bj[4] : (jv);        \
    bd[4] = c4 ? (c3 ? bd[3] : (dv)) : bd[4]; bj[4] = c4 ? (c3 ? bj[3] : (jv)) : bj[4]; \
    bd[3] = c3 ? (c2 ? bd[2] : (dv)) : bd[3]; bj[3] = c3 ? (c2 ? bj[2] : (jv)) : bj[3]; \
    bd[2] = c2 ? (c1 ? bd[1] : (dv)) : bd[2]; bj[2] = c2 ? (c1 ? bj[1] : (jv)) : bj[2]; \
    bd[1] = c1 ? (c0 ? bd[0] : (dv)) : bd[1]; bj[1] = c1 ? (c0 ? bj[0] : (jv)) : bj[1]; \
    bd[0] = c0 ? (dv) : bd[0];              bj[0] = c0 ? (jv) : bj[0];        \
  }                                                                           \
} while (0)

#define LEXLT(dv, jv, ds, js) (((dv) < (ds)) || ((dv) == (ds) && (jv) < (js)))
#define INSERT_TIE(bd, bj, dv, jv) do {                                       \
  if (LEXLT((dv), (jv), bd[5], bj[5])) {                                      \
    const bool c0 = LEXLT((dv), (jv), bd[0], bj[0]);                          \
    const bool c1 = LEXLT((dv), (jv), bd[1], bj[1]);                          \
    const bool c2 = LEXLT((dv), (jv), bd[2], bj[2]);                          \
    const bool c3 = LEXLT((dv), (jv), bd[3], bj[3]);                          \
    const bool c4 = LEXLT((dv), (jv), bd[4], bj[4]);                          \
    bd[5] = c4 ? bd[4] : (dv);              bj[5] = c4 ? bj[4] : (jv);        \
    bd[4] = c4 ? (c3 ? bd[3] : (dv)) : bd[4]; bj[4] = c4 ? (c3 ? bj[3] : (jv)) : bj[4]; \
    bd[3] = c3 ? (c2 ? bd[2] : (dv)) : bd[3]; bj[3] = c3 ? (c2 ? bj[2] : (jv)) : bj[3]; \
    bd[2] = c2 ? (c1 ? bd[1] : (dv)) : bd[2]; bj[2] = c2 ? (c1 ? bj[1] : (jv)) : bj[2]; \
    bd[1] = c1 ? (c0 ? bd[0] : (dv)) : bd[1]; bj[1] = c1 ? (c0 ? bj[0] : (jv)) : bj[1]; \
    bd[0] = c0 ? (dv) : bd[0];              bj[0] = c0 ? (jv) : bj[0];        \
  }                                                                           \
} while (0)

__device__ __forceinline__ f32x16 zero16() {
  f32x16 v;
#pragma unroll
  for (int i = 0; i < 16; ++i) v[i] = 0.f;
  return v;
}

__device__ __forceinline__ unsigned short bf16_rne(float x) {
  unsigned u = __float_as_uint(x);
  u += 0x7fffu + ((u >> 16) & 1u);
  return (unsigned short)(u >> 16);
}
__device__ __forceinline__ float bf16_tof(unsigned short h) {
  return __uint_as_float(((unsigned)h) << 16);
}

// ---------------------------------------------------------------------------
// Prep: sq + exact 3-term bf16 split (x = a+b+c), fragment-major layout:
// element (tile, ks, lane=(khalf<<5)|row, j) at tile*2048 + ks*512 + lane*8+j
// with feature = ks*16 + khalf*8 + j. Tiles 625..627 zeroed (B-side pad).
// ---------------------------------------------------------------------------
__global__ void prep_kernel(const float* __restrict__ x, short* __restrict__ xa,
                            short* __restrict__ xb, short* __restrict__ xc,
                            float* __restrict__ sq) {
  const int n = blockIdx.x * blockDim.x + threadIdx.x;
  if (n >= PREP_TILES * 32) return;
  const int tile = n >> 5, row = n & 31;
  unsigned short a[FDIM], b[FDIM], c[FDIM];
  float s = 0.f;
  if (n < N_NODES) {
    const float4* r4 = (const float4*)(x + (size_t)n * FDIM);
#pragma unroll
    for (int q = 0; q < 16; ++q) {
      const float4 v = r4[q];
      const float vv[4] = {v.x, v.y, v.z, v.w};
#pragma unroll
      for (int e = 0; e < 4; ++e) {
        const float xv = vv[e];
        s = fmaf(xv, xv, s);
        const unsigned short ua = bf16_rne(xv);
        const float r1 = xv - bf16_tof(ua);      // exact
        const unsigned short ub = bf16_rne(r1);
        const float r2 = r1 - bf16_tof(ub);      // exact
        a[q * 4 + e] = ua; b[q * 4 + e] = ub; c[q * 4 + e] = bf16_rne(r2);
      }
    }
  } else {
#pragma unroll
    for (int f = 0; f < FDIM; ++f) { a[f] = 0; b[f] = 0; c[f] = 0; }
    s = __builtin_inff();
  }
  sq[n] = s;
#pragma unroll
  for (int ks = 0; ks < 4; ++ks) {
#pragma unroll
    for (int hh = 0; hh < 2; ++hh) {
      short8 va, vb, vc;
#pragma unroll
      for (int j = 0; j < 8; ++j) {
        const int f = ks * 16 + hh * 8 + j;
        va[j] = (short)a[f]; vb[j] = (short)b[f]; vc[j] = (short)c[f];
      }
      const size_t off = (size_t)tile * 2048 + ks * 512 + (size_t)((hh << 5) | row) * 8;
      *(short8*)(xa + off) = va;
      *(short8*)(xb + off) = vb;
      *(short8*)(xc + off) = vc;
    }
  }
}

// ---------------------------------------------------------------------------
// bf16 MFMA kNN scan: 4-wave blocks; A-tile double-buffered in LDS (shared),
// one wave = one B-tile (32 centers) -> disjoint outputs, no cross-wave
// merge. One barrier per tile; next-tile global loads hide under compute.
// ---------------------------------------------------------------------------
__device__ __forceinline__ void load_frag(const short* __restrict__ xa,
                                          const short* __restrict__ xb,
                                          const short* __restrict__ xc, int t,
                                          int lane, short8 (&Fa)[4],
                                          short8 (&Fb)[4], short8 (&Fc)[4]) {
  const size_t tb = (size_t)t * 2048 + (size_t)lane * 8;
#pragma unroll
  for (int ks = 0; ks < 4; ++ks) {
    Fa[ks] = *(const short8*)(xa + tb + ks * 512);
    Fb[ks] = *(const short8*)(xb + tb + ks * 512);
    Fc[ks] = *(const short8*)(xc + tb + ks * 512);
  }
}

// Selection (verified): fused min/argmin/runner-up + rare exact full ladder.
__device__ __forceinline__ void select6(const f32x16& acc,
                                        const float (&sqa)[16], int jbase,
                                        float (&bd)[KNN], int (&bj)[KNN]) {
  float key[16];
#pragma unroll
  for (int r = 0; r < 16; ++r) key[r] = fmaf(-2.f, acc[r], sqa[r]);  // sq_j-2dot
  float m0 = key[0], m1 = __builtin_inff();
  int j0 = jbase + ROFF(0);
#pragma unroll
  for (int r = 1; r < 16; ++r) {
    const float kr = key[r];
    const bool lt = kr < m0;
    m1 = fminf(m1, lt ? m0 : kr);
    j0 = lt ? (jbase + ROFF(r)) : j0;
    m0 = lt ? kr : m0;
  }
  if (__any(m0 < bd[5])) {
    if (__any(m1 < bd[5])) {
#pragma unroll
      for (int r = 0; r < 16; ++r) { INSERT_CAND(bd, bj, key[r], jbase + ROFF(r)); }
    } else {
      INSERT_CAND(bd, bj, m0, j0);
    }
  }
}

__device__ __forceinline__ void xmerge(float (&bd)[KNN], int (&bj)[KNN]) {
  float od[KNN];
  int oj[KNN];
#pragma unroll
  for (int k = 0; k < KNN; ++k) {
    od[k] = __shfl_xor(bd[k], 32);
    oj[k] = __shfl_xor(bj[k], 32);
  }
#pragma unroll
  for (int k = 0; k < KNN; ++k) INSERT_TIE(bd, bj, od[k], oj[k]);
}

__global__ __launch_bounds__(256, 2) void knn_bf16_kernel(
    const short* __restrict__ xa, const short* __restrict__ xb,
    const short* __restrict__ xc, const float* __restrict__ sq,
    float* __restrict__ cand_d, unsigned short* __restrict__ cand_js,
    int* __restrict__ knn_idx, int nchunks) {
  __shared__ __align__(16) short sa[2][2048];
  __shared__ __align__(16) short sb[2][2048];
  __shared__ __align__(16) short sc[2][2048];
  const int tid = threadIdx.x;
  const int lane = tid & 63;
  const int w = tid >> 6;              // wave 0..3
  const int ct = blockIdx.x * 4 + w;   // this wave's B-tile, 0..627 (>=625 pad)
  const int jc = blockIdx.y;           // 0..nchunks-1
  const int h = lane >> 5, col = lane & 31;

  // One B-tile (32 centers) resident in VGPRs for the whole chunk scan.
  short8 Ba[4], Bb[4], Bc[4];
  load_frag(xa, xb, xc, ct, lane, Ba, Bb, Bc);

  float bd[KNN];
  int bj[KNN];
#pragma unroll
  for (int k = 0; k < KNN; ++k) { bd[k] = __builtin_inff(); bj[k] = 0; }

  const int tbeg = jc * TPC;
  int tend = tbeg + TPC;
  if (tend > NTILES) tend = NTILES;

  const int t8 = tid * 8;  // this thread's 16B slice of each 4KB tile array
  // Prologue: stage tile tbeg into buffer 0.
  {
    const size_t tb = (size_t)tbeg * 2048;
    *(short8*)(sa[0] + t8) = *(const short8*)(xa + tb + t8);
    *(short8*)(sb[0] + t8) = *(const short8*)(xb + tb + t8);
    *(short8*)(sc[0] + t8) = *(const short8*)(xc + tb + t8);
  }
  __syncthreads();

  int cur = 0;
  for (int t = tbeg; t < tend; ++t) {
    // Issue next-tile loads into regs; latency hides under this tile's MFMAs.
    short8 nxa, nxb, nxc;
    const bool have_next = (t + 1 < tend);
    if (have_next) {
      const size_t tb1 = (size_t)(t + 1) * 2048;
      nxa = *(const short8*)(xa + tb1 + t8);
      nxb = *(const short8*)(xb + tb1 + t8);
      nxc = *(const short8*)(xc + tb1 + t8);
    }

    f32x16 acc = zero16();
    const int la8 = lane * 8;
#pragma unroll
    for (int ks = 0; ks < 4; ++ks) {
      // Per-ks transient A-frags from LDS (12 VGPRs, not 48).
      const short8 Aa = *(const short8*)(sa[cur] + ks * 512 + la8);
      const short8 Ab = *(const short8*)(sb[cur] + ks * 512 + la8);
      const short8 Ac = *(const short8*)(sc[cur] + ks * 512 + la8);
      // Chain order identical to the verified comp_tile: aa,ab,ba,ac,ca,bb.
      acc = MFMAB(Aa, Ba[ks], acc);
      acc = MFMAB(Aa, Bb[ks], acc);
      acc = MFMAB(Ab, Ba[ks], acc);
      acc = MFMAB(Aa, Bc[ks], acc);
      acc = MFMAB(Ac, Ba[ks], acc);
      acc = MFMAB(Ab, Bb[ks], acc);
    }
    // sq loads after the chain (verified values; short live range).
    const int sbase = t * 32 + 4 * h;
    float4 S4[4];
#pragma unroll
    for (int g = 0; g < 4; ++g) S4[g] = *(const float4*)(sq + sbase + 8 * g);
    const float sqa[16] = {S4[0].x, S4[0].y, S4[0].z, S4[0].w,
                           S4[1].x, S4[1].y, S4[1].z, S4[1].w,
                           S4[2].x, S4[2].y, S4[2].z, S4[2].w,
                           S4[3].x, S4[3].y, S4[3].z, S4[3].w};
    select6(acc, sqa, t * 32 + 4 * h, bd, bj);

    // Write next tile into the OTHER buffer; single barrier suffices:
    // reads of buf[cur] (this iter) and its rewrite (next iter) are
    // separated by this barrier; writes here never touch buf[cur].
    if (have_next) {
      *(short8*)(sa[cur ^ 1] + t8) = nxa;
      *(short8*)(sb[cur ^ 1] + t8) = nxb;
      *(short8*)(sc[cur ^ 1] + t8) = nxc;
    }
    __syncthreads();
    cur ^= 1;
  }

  // Merge the two row-halves (lane <-> lane^32) lexicographically.
  xmerge(bd, bj);

  if (h == 0) {
    const int i = ct * 32 + col;  // >= 20000 only for pad tiles 625..627
    if (i < N_NODES) {
      if (nchunks == 1) {
#pragma unroll
        for (int k = 0; k < KNN; ++k) knn_idx[(size_t)i * KNN + k] = bj[k];
      } else {
#pragma unroll
        for (int k = 0; k < KNN; ++k) {
          const size_t off = ((size_t)jc * KNN + k) * N_PAD + i;
          cand_d[off] = bd[k];
          cand_js[off] = (unsigned short)bj[k];
        }
      }
    }
  }
}

// Merge u16-j chunk candidates (ascending jc = ascending j ranges preserves
// the lowest-j-wins tie discipline; per-chunk lists already sorted asc).
__global__ void knn_merge_u16_kernel(const float* __restrict__ cand_d,
                                     const unsigned short* __restrict__ cand_js,
                                     int* __restrict__ knn_idx, int nchunks) {
  const int i = blockIdx.x * blockDim.x + threadIdx.x;
  if (i >= N_NODES) return;
  float bd[KNN];
  int bj[KNN];
#pragma unroll
  for (int k = 0; k < KNN; ++k) { bd[k] = __builtin_inff(); bj[k] = 0; }
  for (int jc = 0; jc < nchunks; ++jc) {
#pragma unroll
    for (int k = 0; k < KNN; ++k) {
      const size_t off = ((size_t)jc * KNN + k) * N_PAD + i;
      const float d = cand_d[off];
      const int j = (int)cand_js[off];
      INSERT_CAND(bd, bj, d, j);
    }
  }
#pragma unroll
  for (int k = 0; k < KNN; ++k) knn_idx[(size_t)i * KNN + k] = bj[k];
}

// ---------------------------------------------------------------------------
// Fallback VALU path (proven round-4) -- tiny-ws only.
// ---------------------------------------------------------------------------
__global__ void sq_kernel(const float* __restrict__ x, float* __restrict__ sq) {
  const int i = blockIdx.x * blockDim.x + threadIdx.x;
  if (i >= N_NODES) return;
  const float4* r4 = (const float4*)(x + (size_t)i * FDIM);
  float s = 0.f;
#pragma unroll
  for (int q = 0; q < 16; ++q) {
    const float4 a = r4[q];
    s = fmaf(a.x, a.x, s);
    s = fmaf(a.y, a.y, s);
    s = fmaf(a.z, a.z, s);
    s = fmaf(a.w, a.w, s);
  }
  sq[i] = s;
}

__global__ __launch_bounds__(RPB, 2) void knn_partial_kernel(
    const float* __restrict__ x, const float* __restrict__ sq,
    float* __restrict__ cand_d, int* __restrict__ cand_j,
    int* __restrict__ knn_idx, int jchunk, int nchunks) {
  __shared__ __align__(16) float xs[TILE_J][FDIM + 4];
  __shared__ float sqs[TILE_J];
  const int tid = threadIdx.x;
  const int i = blockIdx.x * RPB + tid;
  const bool valid = i < N_NODES;
  const int jc = blockIdx.y;

  float xi[FDIM];
  float sqi = 0.f;
  if (valid) {
    const float4* r4 = (const float4*)(x + (size_t)i * FDIM);
#pragma unroll
    for (int q = 0; q < 16; ++q) {
      const float4 a = r4[q];
      xi[q * 4 + 0] = a.x; xi[q * 4 + 1] = a.y;
      xi[q * 4 + 2] = a.z; xi[q * 4 + 3] = a.w;
    }
    sqi = sq[i];
  } else {
#pragma unroll
    for (int f = 0; f < FDIM; ++f) xi[f] = 0.f;
  }
#pragma unroll
  for (int f = 0; f < FDIM; ++f) asm volatile("" : "+v"(xi[f]));

  float bd[KNN];
  int bj[KNN];
#pragma unroll
  for (int k = 0; k < KNN; ++k) { bd[k] = __builtin_inff(); bj[k] = 0; }

  const int jcbase = jc * jchunk;
  for (int t0 = 0; t0 < jchunk; t0 += TILE_J) {
    const int jt = jcbase + t0;
    __syncthreads();
    {
      const int jj = tid >> 2;
      const int f0 = (tid & 3) * 16;
      const int j = jt + jj;
      float4* dst = (float4*)&xs[jj][f0];
      if (j < N_NODES) {
        const float4* src = (const float4*)(x + (size_t)j * FDIM + f0);
        dst[0] = src[0];
        dst[1] = src[1];
        dst[2] = src[2];
        dst[3] = src[3];
      } else {
        const float4 z = make_float4(0.f, 0.f, 0.f, 0.f);
        dst[0] = z; dst[1] = z; dst[2] = z; dst[3] = z;
      }
      if (tid < TILE_J) {
        const int j2 = jt + tid;
        sqs[tid] = (j2 < N_NODES) ? sq[j2] : 0.f;
      }
    }
    __syncthreads();
    const int rem = N_NODES - jt;
    const int jmax = rem < TILE_J ? rem : TILE_J;
    for (int jj = 0; jj < jmax; ++jj) {
      const float4* xr4 = (const float4*)&xs[jj][0];
      float dot = 0.f;
#pragma unroll
      for (int q = 0; q < 16; ++q) {
        const float4 v = xr4[q];
        dot = fmaf(xi[q * 4 + 0], v.x, dot);
        dot = fmaf(xi[q * 4 + 1], v.y, dot);
        dot = fmaf(xi[q * 4 + 2], v.z, dot);
        dot = fmaf(xi[q * 4 + 3], v.w, dot);
      }
      const float d = fmaf(-2.f, dot, sqi + sqs[jj]);
      const int j = jt + jj;
      INSERT_CAND(bd, bj, d, j);
    }
  }

  if (valid) {
    if (nchunks == 1) {
#pragma unroll
      for (int k = 0; k < KNN; ++k) knn_idx[(size_t)i * KNN + k] = bj[k];
    } else {
#pragma unroll
      for (int k = 0; k < KNN; ++k) {
        const size_t off = ((size_t)jc * KNN + k) * N_PAD + i;
        cand_d[off] = bd[k];
        cand_j[off] = bj[k];
      }
    }
  }
}

__global__ void knn_merge_kernel(const float* __restrict__ cand_d,
                                 const int* __restrict__ cand_j,
                                 int* __restrict__ knn_idx, int nchunks) {
  const int i = blockIdx.x * blockDim.x + threadIdx.x;
  if (i >= N_NODES) return;
  float bd[KNN];
  int bj[KNN];
#pragma unroll
  for (int k = 0; k < KNN; ++k) { bd[k] = __builtin_inff(); bj[k] = 0; }
  for (int jc = 0; jc < nchunks; ++jc) {
#pragma unroll
    for (int k = 0; k < KNN; ++k) {
      const size_t off = ((size_t)jc * KNN + k) * N_PAD + i;
      const float d = cand_d[off];
      const int j = cand_j[off];
      INSERT_CAND(bd, bj, d, j);
    }
  }
#pragma unroll
  for (int k = 0; k < KNN; ++k) knn_idx[(size_t)i * KNN + k] = bj[k];
}

__global__ __launch_bounds__(HID) void mlp_kernel(
    const float* __restrict__ x, const int* __restrict__ knn_idx,
    const float* __restrict__ W1, const float* __restrict__ b1,
    const float* __restrict__ W2, const float* __restrict__ b2,
    float* __restrict__ out) {
  __shared__ float xi_s[FDIM];
  __shared__ float xd_s[KNN][FDIM];
  __shared__ float h1_s[KNN][HID];
  __shared__ int nb[KNN];
  const int i = blockIdx.x;
  const int t = threadIdx.x;
  if (t < KNN) {
    const int v = knn_idx[(size_t)i * KNN + t];
    nb[t] = ((unsigned)v < (unsigned)N_NODES) ? v : 0;  // clamp: cannot fault
  }
  if (t < FDIM) xi_s[t] = x[(size_t)i * FDIM + t];
  __syncthreads();
  for (int e = t; e < KNN * FDIM; e += HID) {
    const int k = e >> 6;
    const int f = e & 63;
    xd_s[k][f] = x[(size_t)nb[k] * FDIM + f] - xi_s[f];
  }
  __syncthreads();

  float s0 = b1[t];
  for (int f = 0; f < FDIM; ++f) {
    const float w = W1[f * HID + t];
    s0 = fmaf(xi_s[f], w, s0);
  }
  float acc[KNN];
#pragma unroll
  for (int k = 0; k < KNN; ++k) acc[k] = s0;
  for (int f = 0; f < FDIM; ++f) {
    const float w = W1[(FDIM + f) * HID + t];
#pragma unroll
    for (int k = 0; k < KNN; ++k) acc[k] = fmaf(xd_s[k][f], w, acc[k]);
  }
#pragma unroll
  for (int k = 0; k < KNN; ++k) h1_s[k][t] = fmaxf(acc[k], 0.f);
  __syncthreads();

  float acc2[KNN];
  const float bb = b2[t];
#pragma unroll
  for (int k = 0; k < KNN; ++k) acc2[k] = bb;
  for (int h = 0; h < HID; ++h) {
    const float w = W2[h * HID + t];
#pragma unroll
    for (int k = 0; k < KNN; ++k) acc2[k] = fmaf(h1_s[k][h], w, acc2[k]);
  }
  float m = acc2[0];
#pragma unroll
  for (int k = 1; k < KNN; ++k) m = fmaxf(m, acc2[k]);
  out[(size_t)i * HID + t] = m;
}

extern "C" void kernel_launch(void* const* d_in, const int* in_sizes, int n_in,
                              void* d_out, int out_size, void* d_ws, size_t ws_size,
                              hipStream_t stream) {
  const float* x  = (const float*)d_in[0];
  const float* W1 = (const float*)d_in[2];
  const float* b1 = (const float*)d_in[3];
  const float* W2 = (const float*)d_in[4];
  const float* b2 = (const float*)d_in[5];
  float* out = (float*)d_out;
  char* ws = (char*)d_ws;
  const size_t PER_CHUNK = (size_t)KNN * N_PAD * 8;  // 983,040 B (fallback)

  if (ws_size >= 0x998000) {
    // MFMA layout (10,059,776 B required; inferred ws >= 10,420,224):
    //   0x000000 sq      (20096 f32 used; 0x20000 reserved)
    //   0x020000 xa      (628*2048 s16 = 2,572,288 B) -> 0x294000
    //   0x294000 xb      -> 0x508000
    //   0x508000 xc      -> 0x77C000
    //   0x77C000 cand_d  (3*6*20480 f32 = 1,474,560 B) -> 0x8E4000
    //   0x8E4000 cand_js (3*6*20480 u16 = 737,280 B)  -> 0x998000
    //   knn aliases xa at 0x20000 (xa dead after the scan).
    float* sq   = (float*)ws;
    short* xa   = (short*)(ws + 0x20000);
    short* xb   = (short*)(ws + 0x294000);
    short* xc   = (short*)(ws + 0x508000);
    float* cand_d = (float*)(ws + 0x77C000);
    unsigned short* cand_js = (unsigned short*)(ws + 0x8E4000);
    int* knn = (int*)(ws + 0x20000);

    prep_kernel<<<dim3((PREP_TILES * 32 + 255) / 256), dim3(256), 0, stream>>>(
        x, xa, xb, xc, sq);
    knn_bf16_kernel<<<dim3(NBLK, NCHUNK), dim3(256), 0, stream>>>(
        xa, xb, xc, sq, cand_d, cand_js, knn, NCHUNK);
    knn_merge_u16_kernel<<<dim3((N_NODES + 255) / 256), dim3(256), 0, stream>>>(
        cand_d, cand_js, knn, NCHUNK);
    mlp_kernel<<<dim3(N_NODES), dim3(HID), 0, stream>>>(x, knn, W1, b1, W2, b2, out);
  } else {
    // Fallback: round-4 layout (sq | knn | cand at 0x90000)
    float* sq = (float*)ws;
    int* knn  = (int*)(ws + (size_t)N_PAD * 4);
    const size_t BASE = 0x90000;
    int nc = 1;
    if (ws_size > BASE + PER_CHUNK) {
      size_t fit = (ws_size - BASE) / PER_CHUNK;
      nc = fit < (size_t)MAX_CHUNKS ? (int)fit : MAX_CHUNKS;
      if (nc < 1) nc = 1;
    }
    int jchunk = ((N_NODES + nc - 1) / nc + TILE_J - 1) / TILE_J * TILE_J;
    float* cand_d = (float*)(ws + BASE);
    int* cand_j = (int*)(ws + BASE + (size_t)nc * KNN * N_PAD * 4);

    sq_kernel<<<dim3((N_NODES + 255) / 256), dim3(256), 0, stream>>>(x, sq);
    knn_partial_kernel<<<dim3((N_NODES + RPB - 1) / RPB, nc), dim3(RPB), 0, stream>>>(
        x, sq, cand_d, cand_j, knn, jchunk, nc);
    if (nc > 1) {
      knn_merge_kernel<<<dim3((N_NODES + 255) / 256), dim3(256), 0, stream>>>(
          cand_d, cand_j, knn, nc);
    }
    mlp_kernel<<<dim3(N_NODES), dim3(HID), 0, stream>>>(x, knn, W1, b1, W2, b2, out);
  }
}